// Round 18
// baseline (1598.075 us; speedup 1.0000x reference)
//
#include <hip/hip_runtime.h>
#include <hip/hip_bf16.h>
#include <cstdint>

typedef __hip_bfloat16 bf16;
typedef __attribute__((ext_vector_type(8))) short v8s;
typedef __attribute__((ext_vector_type(4))) float v4f;

#define SWZ(base, row, bytecol) ((base) + (row) * 128 + ((bytecol) ^ (((row) & 7) << 4)))

__device__ __forceinline__ void gload16(const void* g, void* l) {
  __builtin_amdgcn_global_load_lds((__attribute__((address_space(1))) void*)g,
                                   (__attribute__((address_space(3))) void*)l, 16, 0, 0);
}

__device__ __forceinline__ v4f mfma16(v8s a, v8s b, v4f c) {
  return __builtin_amdgcn_mfma_f32_16x16x32_bf16(a, b, c, 0, 0, 0);
}

// bare v_exp_f32 (2^x) — avoids OCML exp2f fixup path
__device__ __forceinline__ float exp2_raw(float x) {
  float r;
  asm("v_exp_f32 %0, %1" : "=v"(r) : "v"(x));
  return r;
}

// raw barrier: lgkmcnt(0) for own-LDS visibility, NO vmcnt drain (keeps prefetch in flight)
__device__ __forceinline__ void pipe_barrier() {
  asm volatile("s_waitcnt lgkmcnt(0)" ::: "memory");
  __builtin_amdgcn_s_barrier();
  asm volatile("" ::: "memory");
}

__device__ __forceinline__ float bu2f(unsigned short u) {
  return __uint_as_float((unsigned)u << 16);
}
__device__ __forceinline__ unsigned short f2bu(float f) {
  bf16 b = __float2bfloat16(f);
  return *(unsigned short*)&b;
}
__device__ __forceinline__ unsigned packbf(float a, float b) {
  return (unsigned)f2bu(a) | ((unsigned)f2bu(b) << 16);
}

__device__ __forceinline__ float blocksum(float v, float* red, int tid) {
#pragma unroll
  for (int o = 32; o > 0; o >>= 1) v += __shfl_xor(v, o);
  if ((tid & 63) == 0) red[tid >> 6] = v;
  __syncthreads();
  float r = red[0] + red[1] + red[2] + red[3];
  __syncthreads();
  return r;
}

// ---------------- xs f32[8192][80] -> bf16[8192][128] (zero-pad K) ----------------
__global__ __launch_bounds__(256) void xsconv_kernel(const float* __restrict__ xs,
                                                     bf16* __restrict__ dst) {
  const int i = blockIdx.x * 256 + threadIdx.x;
  if (i >= 8192 * 128) return;
  const int row = i >> 7, col = i & 127;
  dst[i] = __float2bfloat16(col < 80 ? xs[row * 80 + col] : 0.0f);
}

// ---------------- emb_w f32[80][512] -> bf16[512][128] transposed+padded ----------------
__global__ __launch_bounds__(256) void embwconv_kernel(const float* __restrict__ w,
                                                       bf16* __restrict__ dst) {
  const int i = blockIdx.x * 256 + threadIdx.x;
  if (i >= 512 * 128) return;
  const int n = i >> 7, k = i & 127;
  dst[i] = __float2bfloat16(k < 80 ? w[k * 512 + n] : 0.0f);
}

// ---------------- fused LN(emb)->relu->posenc->x ; LN1(x)->h ; writes both stacks ----------------
__global__ __launch_bounds__(256) void posenc_ln_kernel(
    const bf16* __restrict__ e, const float* __restrict__ g, const float* __restrict__ beta,
    const float* __restrict__ ln1g, const float* __restrict__ ln1b, bf16* __restrict__ x,
    bf16* __restrict__ h, int zdim) {
  const int tok = blockIdx.x;  // 0..8191
  const int tid = threadIdx.x;
  __shared__ float red[4];
  const int c0 = 2 * tid, c1 = 2 * tid + 1;
  const unsigned ev = *(const unsigned*)(e + (long)tok * 512 + c0);
  float v0 = bu2f((unsigned short)ev);
  float v1 = bu2f((unsigned short)(ev >> 16));
  const float mean = blocksum(v0 + v1, red, tid) * (1.0f / 512.0f);
  const float d0 = v0 - mean, d1 = v1 - mean;
  const float var = blocksum(d0 * d0 + d1 * d1, red, tid) * (1.0f / 512.0f);
  const float inv = rsqrtf(var + 1e-12f);
  const float r0 = fmaxf(d0 * inv * g[c0] + beta[c0], 0.0f);
  const float r1 = fmaxf(d1 * inv * g[c1] + beta[c1], 0.0f);
  const int t = tok & 1023;
  const float a = (float)t * __expf((float)c0 * (-9.210340371976184f / 512.0f));
  float sa, ca;
  __sincosf(a, &sa, &ca);
  const float x0 = r0 * 22.627416997969522f + sa;
  const float x1 = r1 * 22.627416997969522f + ca;
  // LN1
  const float m2 = blocksum(x0 + x1, red, tid) * (1.0f / 512.0f);
  const float e0 = x0 - m2, e1 = x1 - m2;
  const float vv = blocksum(e0 * e0 + e1 * e1, red, tid) * (1.0f / 512.0f);
  const float iv = rsqrtf(vv + 1e-12f);
  const float h0 = e0 * iv * ln1g[c0] + ln1b[c0];
  const float h1 = e1 * iv * ln1g[c1] + ln1b[c1];
  const unsigned xp = packbf(x0, x1);
  const unsigned hp = packbf(h0, h1);
  for (int z = 0; z < zdim; ++z) {
    const long row = tok + (long)z * 8192;
    *(unsigned*)(x + row * 512 + c0) = xp;
    *(unsigned*)(h + row * 512 + c0) = hp;
  }
}

// ---------------- fused residual add + LayerNorm, ONE WAVE PER ROW ----------------
template <int FINAL>
__global__ __launch_bounds__(256) void add_ln_kernel(bf16* __restrict__ x,
                                                     const bf16* __restrict__ y,
                                                     const float* __restrict__ g,
                                                     const float* __restrict__ bta,
                                                     void* __restrict__ outp) {
  const int lane = threadIdx.x & 63;
  const long row = (long)blockIdx.x * 4 + (threadIdx.x >> 6);
  const int c = lane * 8;
  const long i0 = row * 512 + c;
  const uint4 xv = *(const uint4*)(x + i0);
  const uint4 yv = *(const uint4*)(y + i0);
  const unsigned* xp = (const unsigned*)&xv;
  const unsigned* yp = (const unsigned*)&yv;
  float v[8];
#pragma unroll
  for (int j = 0; j < 4; ++j) {
    v[2 * j] = bu2f((unsigned short)xp[j]) + bu2f((unsigned short)yp[j]);
    v[2 * j + 1] = bu2f((unsigned short)(xp[j] >> 16)) + bu2f((unsigned short)(yp[j] >> 16));
  }
  if (!FINAL) {
    uint4 w;
    unsigned* wp = (unsigned*)&w;
#pragma unroll
    for (int j = 0; j < 4; ++j) wp[j] = packbf(v[2 * j], v[2 * j + 1]);
    *(uint4*)(x + i0) = w;
  }
  float s = ((v[0] + v[1]) + (v[2] + v[3])) + ((v[4] + v[5]) + (v[6] + v[7]));
#pragma unroll
  for (int o = 32; o > 0; o >>= 1) s += __shfl_xor(s, o);
  const float mean = s * (1.0f / 512.0f);
  float q = 0.0f;
#pragma unroll
  for (int j = 0; j < 8; ++j) {
    v[j] -= mean;
    q += v[j] * v[j];
  }
#pragma unroll
  for (int o = 32; o > 0; o >>= 1) q += __shfl_xor(q, o);
  const float inv = rsqrtf(q * (1.0f / 512.0f) + 1e-12f);
  const float4 g0 = *(const float4*)(g + c);
  const float4 g1 = *(const float4*)(g + c + 4);
  const float4 b0 = *(const float4*)(bta + c);
  const float4 b1 = *(const float4*)(bta + c + 4);
  float o0 = v[0] * inv * g0.x + b0.x, o1 = v[1] * inv * g0.y + b0.y;
  float o2 = v[2] * inv * g0.z + b0.z, o3 = v[3] * inv * g0.w + b0.w;
  float o4 = v[4] * inv * g1.x + b1.x, o5 = v[5] * inv * g1.y + b1.y;
  float o6 = v[6] * inv * g1.z + b1.z, o7 = v[7] * inv * g1.w + b1.w;
  if (FINAL) {
    float4* o = (float4*)((float*)outp + i0);
    o[0] = make_float4(o0, o1, o2, o3);
    o[1] = make_float4(o4, o5, o6, o7);
  } else {
    uint4 w;
    w.x = packbf(o0, o1);
    w.y = packbf(o2, o3);
    w.z = packbf(o4, o5);
    w.w = packbf(o6, o7);
    *(uint4*)((bf16*)outp + i0) = w;
  }
}

// ---------------- weight convert f32[K][N] -> bf16[N][K] (transposed) ----------------
__global__ __launch_bounds__(256) void trconv_kernel(const float* __restrict__ src,
                                                     bf16* __restrict__ dst, int K, int N,
                                                     long src_lstride, long dst_lstride) {
  __shared__ float tile[32][33];
  src += (long)blockIdx.z * src_lstride;
  dst += (long)blockIdx.z * dst_lstride;
  const int n0 = blockIdx.x * 32, k0 = blockIdx.y * 32;
  const int tx = threadIdx.x & 31, ty = threadIdx.x >> 5;
#pragma unroll
  for (int i = 0; i < 32; i += 8)
    tile[ty + i][tx] = src[(long)(k0 + ty + i) * N + n0 + tx];
  __syncthreads();
#pragma unroll
  for (int i = 0; i < 32; i += 8)
    dst[(long)(n0 + ty + i) * K + k0 + tx] = __float2bfloat16(tile[tx][ty + i]);
}

__global__ void biascat_kernel(const float* bq, const float* bk, const float* bv, float* o) {
  const int i = blockIdx.x * 256 + threadIdx.x;
  if (i >= 6 * 1536) return;
  const int l = i / 1536, n = i % 1536;
  o[i] = (n < 512) ? bq[l * 512 + n] : (n < 1024) ? bk[l * 512 + n - 512] : bv[l * 512 + n - 1024];
}

__global__ void maskout_kernel(const int* m, float* o, int n) {
  const int i = blockIdx.x * 256 + threadIdx.x;
  if (i < n) o[i] = m[i] ? 1.0f : 0.0f;
}

// ---------------- GEMM 128x128: C = (A @ W^T + bias) * sc ----------------
// BK=64, XOR-swizzled LDS, double-buffered, operand-resident XCD partition.
template <bool RELU>
__global__ __launch_bounds__(256) void gemm_kernel(const bf16* __restrict__ A,
                                                   const bf16* __restrict__ W,
                                                   const float* __restrict__ bias,
                                                   bf16* __restrict__ outp, int M, int N, int K,
                                                   float qsc, int qcols) {
  __shared__ __align__(16) bf16 As[2][128 * 64];
  __shared__ __align__(16) bf16 Bs[2][128 * 64];
  const int tid = threadIdx.x, lane = tid & 63, wave = tid >> 6;
  int bx, by;
  {
    const int gx = gridDim.x, gy = gridDim.y;
    const int f = (int)blockIdx.y * gx + (int)blockIdx.x;
    if ((gx & 7) == 0) {
      const int xcd = f & 7;
      const int j = f >> 3;
      const int per = gx >> 3;
      by = j % gy;
      bx = xcd * per + j / gy;
    } else {
      bx = blockIdx.x;
      by = blockIdx.y;
    }
  }
  const int m0 = bx * 128, n0 = by * 128;
  const float sc = (n0 < qcols) ? qsc : 1.0f;
  const int wr = (wave >> 1) * 64, wc = (wave & 1) * 64;
  const int colswz = (((tid & 7) ^ ((tid >> 3) & 7)) * 8);
  const bf16* ag = A + (long)(m0 + (tid >> 3)) * K + colswz;
  const bf16* bg = W + (long)(n0 + (tid >> 3)) * K + colswz;
  char* asb = (char*)As + wave * 1024;
  char* bsb = (char*)Bs + wave * 1024;
  v4f acc[4][4] = {};
  const int frow = lane & 15, fch = lane >> 4;
  const int nk = K >> 6;
#pragma unroll
  for (int i = 0; i < 4; ++i) {
    gload16(ag + (long)i * 32 * K, asb + i * 4096);
    gload16(bg + (long)i * 32 * K, bsb + i * 4096);
  }
  for (int t = 0; t < nk; ++t) {
    const int cur = t & 1;
    asm volatile("s_waitcnt vmcnt(0)" ::: "memory");
    __builtin_amdgcn_s_barrier();
    if (t + 1 < nk) {
      const int k0 = (t + 1) << 6;
      const int nb = (cur ^ 1) * 16384;
#pragma unroll
      for (int i = 0; i < 4; ++i) {
        gload16(ag + k0 + (long)i * 32 * K, asb + nb + i * 4096);
        gload16(bg + k0 + (long)i * 32 * K, bsb + nb + i * 4096);
      }
    }
    const char* Ab = (const char*)As[cur];
    const char* Bb = (const char*)Bs[cur];
#pragma unroll
    for (int kk = 0; kk < 2; ++kk) {
      v8s af[4], bfv[4];
#pragma unroll
      for (int m = 0; m < 4; ++m) {
        const int row = wr + m * 16 + frow;
        af[m] = *(const v8s*)(Ab + row * 128 + (((kk * 4 + fch) * 16) ^ ((row & 7) << 4)));
      }
#pragma unroll
      for (int n = 0; n < 4; ++n) {
        const int row = wc + n * 16 + frow;
        bfv[n] = *(const v8s*)(Bb + row * 128 + (((kk * 4 + fch) * 16) ^ ((row & 7) << 4)));
      }
#pragma unroll
      for (int m = 0; m < 4; ++m)
#pragma unroll
        for (int n = 0; n < 4; ++n)
          acc[m][n] = mfma16(af[m], bfv[n], acc[m][n]);
    }
  }
  float bv[4];
#pragma unroll
  for (int n = 0; n < 4; ++n) bv[n] = bias[n0 + wc + n * 16 + frow];
#pragma unroll
  for (int m = 0; m < 4; ++m) {
#pragma unroll
    for (int n = 0; n < 4; ++n) {
#pragma unroll
      for (int r = 0; r < 4; ++r) {
        const int row = m0 + wr + m * 16 + fch * 4 + r;
        const int col = n0 + wc + n * 16 + frow;
        float v = (acc[m][n][r] + bv[n]) * sc;
        if (RELU) v = fmaxf(v, 0.0f);
        outp[(long)row * N + col] = __float2bfloat16(v);
      }
    }
  }
}

// ---------------- fused flash attention (swapped-QK^T, K direct-from-L2) ----------------
// K fragments are contiguous 16B rows of global K (L2-resident, XCD-colocated) -> no K LDS
// round-trip. V keeps LDS+transpose (fragment needs column access). Q pre-scaled by
// 0.125*log2e -> log2-domain softmax with bare v_exp_f32; defer-rescale; deferred l-reduce.
__global__ __launch_bounds__(512) void attn_kernel(const bf16* __restrict__ qkv,
                                                   bf16* __restrict__ aout, int chunk0) {
  __shared__ __align__(16) char QPs[128 * 128];   // Q tile, then per-wave P strips
  __shared__ __align__(16) char Vs[2][64 * 128];  // V^T: [d][key*2 ^ (((d>>3)^(d&7))<<4)]
  const int tid = threadIdx.x, lane = tid & 63, wave = tid >> 6;
  int qb, bh, zz;
  {
    const int zdim = (int)gridDim.z;            // 1 or 2
    const int nwg = 512 * zdim;
    const int flat = (int)blockIdx.x + 8 * (int)blockIdx.y + 512 * (int)blockIdx.z;
    const int s = (flat & 7) * (nwg >> 3) + (flat >> 3);
    qb = s & 7;
    const int rest = s >> 3;                    // = bh*zdim + zz  (zz fastest)
    zz = rest & (zdim - 1);
    bh = rest >> (zdim >> 1);
  }
  const int chunked = chunk0 + zz;
  const long tb = (long)zz * 8192 + (long)(bh >> 3) * 1024;
  const int hh = bh & 7;
  const int q0 = qb * 128;
  const int sr = tid >> 3, ss = tid & 7;
  const int frow = lane & 15, fch = lane >> 4;
  int kt0 = 0, kt1 = 16;
  if (chunked) {
    kt0 = qb * 2 - 1;
    if (kt0 < 0) kt0 = 0;
    kt1 = qb * 2 + 2;
  }
  // per-lane K fragment base: row frow, d = fch*8 (+32 for half 1)
  const bf16* kbase = qkv + (tb + frow) * 1536 + 512 + hh * 64 + fch * 8;
  // first V tile load + K fragments for kt0 (all in flight during Q staging)
  uint4 vreg;
  {
    const long ro = (tb + kt0 * 64 + sr) * 1536 + hh * 64 + ss * 8;
    vreg = *(const uint4*)(qkv + ro + 1024);
  }
  v8s kf[4][2];
#pragma unroll
  for (int n = 0; n < 4; ++n) {
#pragma unroll
    for (int h = 0; h < 2; ++h)
      kf[n][h] = *(const v8s*)(kbase + (long)(kt0 * 64 + n * 16) * 1536 + h * 32);
  }
#pragma unroll
  for (int p = 0; p < 2; ++p) {
    const int rr = sr + p * 64;
    const uint4 d = *(const uint4*)(qkv + (tb + q0 + rr) * 1536 + hh * 64 + ss * 8);
    *(uint4*)(QPs + rr * 128 + ((ss * 16) ^ ((rr & 7) << 4))) = d;
  }
  pipe_barrier();  // [A] Q visible
  const v8s qa0 = *(const v8s*)SWZ(QPs, wave * 16 + frow, fch * 16);
  const v8s qa1 = *(const v8s*)SWZ(QPs, wave * 16 + frow, 64 + fch * 16);
  // stage V buf0, issue V tile kt0+1
  {
    const bf16* ve = (const bf16*)&vreg;
#pragma unroll
    for (int e = 0; e < 8; ++e) {
      *(bf16*)(Vs[0] + (ss * 8 + e) * 128 + ((sr * 2) ^ (ss << 4) ^ (e << 4))) = ve[e];
    }
  }
  if (kt0 + 1 < kt1) {
    const long ro = (tb + (kt0 + 1) * 64 + sr) * 1536 + hh * 64 + ss * 8;
    vreg = *(const uint4*)(qkv + ro + 1024);
  }
  pipe_barrier();  // [B] buf0 visible
  v4f accv[4] = {};
  float m_run = -1e30f, l_run = 0.0f;
  const int qswz = (frow & 7) << 4;
  char* Pw = QPs + wave * 2048;  // own wave's (dead) Q strip: P[q=frow][key]
  const int qb_ = (q0 + wave * 16 + frow) >> 4;  // chunk row (chunked mask), per-lane const
  int cur = 0;
  for (int kt = kt0; kt < kt1; ++kt) {
    if (kt + 1 < kt1) {
      const bf16* ve = (const bf16*)&vreg;
#pragma unroll
      for (int e = 0; e < 8; ++e) {
        *(bf16*)(Vs[cur ^ 1] + (ss * 8 + e) * 128 + ((sr * 2) ^ (ss << 4) ^ (e << 4))) = ve[e];
      }
      if (kt + 2 < kt1) {
        const long ro = (tb + (kt + 2) * 64 + sr) * 1536 + hh * 64 + ss * 8;
        vreg = *(const uint4*)(qkv + ro + 1024);
      }
    }
    const char* Vc = Vs[cur];
    v4f s4[4];
    __builtin_amdgcn_s_setprio(1);
#pragma unroll
    for (int n = 0; n < 4; ++n) {
      v4f z = {0.f, 0.f, 0.f, 0.f};
      z = mfma16(kf[n][0], qa0, z);  // swapped: S^T tile (log2-domain), lane col = q(frow)
      z = mfma16(kf[n][1], qa1, z);
      s4[n] = z;
    }
    __builtin_amdgcn_s_setprio(0);
    // prefetch K fragments for kt+1 (consumed next iter; hidden under softmax+PV)
    if (kt + 1 < kt1) {
#pragma unroll
      for (int n = 0; n < 4; ++n) {
#pragma unroll
        for (int h = 0; h < 2; ++h)
          kf[n][h] = *(const v8s*)(kbase + (long)((kt + 1) * 64 + n * 16) * 1536 + h * 32);
      }
    }
    if (chunked) {
#pragma unroll
      for (int n = 0; n < 4; ++n)
#pragma unroll
        for (int r = 0; r < 4; ++r) {
          const int kb_ = (kt * 64 + n * 16 + fch * 4 + r) >> 4;
          if (!(kb_ <= qb_ && qb_ - kb_ <= 4)) s4[n][r] = -1e30f;
        }
    }
    // in-lane row max (16 values for q=frow) + 2 cross-group shuffles
    float u0 = fmaxf(fmaxf(s4[0][0], s4[1][0]), fmaxf(s4[2][0], s4[3][0]));
    float u1 = fmaxf(fmaxf(s4[0][1], s4[1][1]), fmaxf(s4[2][1], s4[3][1]));
    float u2 = fmaxf(fmaxf(s4[0][2], s4[1][2]), fmaxf(s4[2][2], s4[3][2]));
    float u3 = fmaxf(fmaxf(s4[0][3], s4[1][3]), fmaxf(s4[2][3], s4[3][3]));
    float mt = fmaxf(fmaxf(u0, u1), fmaxf(u2, u3));
    mt = fmaxf(mt, __shfl_xor(mt, 16));
    mt = fmaxf(mt, __shfl_xor(mt, 32));
    // defer-rescale: only when row max grew past 3.0 log2 units (P <= 8)
    if (!__all(mt <= m_run + 3.0f)) {
      const float mnew = fmaxf(m_run, mt);
      const float esc = exp2_raw(m_run - mnew);
      l_run *= esc;
#pragma unroll
      for (int f = 0; f < 4; ++f)
#pragma unroll
        for (int r = 0; r < 4; ++r) accv[f][r] *= esc;
      m_run = mnew;
    }
#pragma unroll
    for (int n = 0; n < 4; ++n)
#pragma unroll
      for (int r = 0; r < 4; ++r) s4[n][r] = exp2_raw(s4[n][r] - m_run);
    l_run += ((s4[0][0] + s4[1][0]) + (s4[2][0] + s4[3][0])) +
             ((s4[0][1] + s4[1][1]) + (s4[2][1] + s4[3][1])) +
             ((s4[0][2] + s4[1][2]) + (s4[2][2] + s4[3][2])) +
             ((s4[0][3] + s4[1][3]) + (s4[2][3] + s4[3][3]));
    // P[q=frow][key = fch*4 + r + 16n] -> 4x 8B swizzled writes
#pragma unroll
    for (int n = 0; n < 4; ++n) {
      uint2 w;
      w.x = packbf(s4[n][0], s4[n][1]);
      w.y = packbf(s4[n][2], s4[n][3]);
      *(uint2*)(Pw + frow * 128 + ((fch * 8 + 32 * n) ^ qswz)) = w;
    }
    const v8s pa0 = *(const v8s*)(Pw + frow * 128 + ((fch * 16) ^ qswz));
    const v8s pa1 = *(const v8s*)(Pw + frow * 128 + ((64 + fch * 16) ^ qswz));
    __builtin_amdgcn_s_setprio(1);
#pragma unroll
    for (int f = 0; f < 4; ++f) {
      const int vh = (((f * 2 + (frow >> 3)) ^ (frow & 7)) & 7) << 4;
      const int drow = (f * 16 + frow) * 128;
      const v8s vb0 = *(const v8s*)(Vc + drow + ((fch * 16) ^ vh));
      const v8s vb1 = *(const v8s*)(Vc + drow + ((64 + fch * 16) ^ vh));
      accv[f] = mfma16(vb0, pa0, accv[f]);  // O^T: lane col = q(frow), row = d
      accv[f] = mfma16(vb1, pa1, accv[f]);
    }
    __builtin_amdgcn_s_setprio(0);
    pipe_barrier();
    cur ^= 1;
  }
  // deferred cross-lane l reduction (esc was row-uniform each tile)
  l_run += __shfl_xor(l_run, 16);
  l_run += __shfl_xor(l_run, 32);
  const float rl = 1.0f / l_run;
  const long orow = (tb + q0 + wave * 16 + frow) * 512 + hh * 64;
#pragma unroll
  for (int f = 0; f < 4; ++f) {
    uint2 u;
    u.x = packbf(accv[f][0] * rl, accv[f][1] * rl);
    u.y = packbf(accv[f][2] * rl, accv[f][3] * rl);
    *(uint2*)(aout + orow + f * 16 + fch * 4) = u;
  }
}

struct Bufs {
  bf16 *Wqkv, *Wo, *W1, *W2;
  float* bqkv;
  bf16 *xsbf, *wemb, *e;
  bf16* x;
  bf16 *h, *qkv, *attn;
  size_t need;
};

static Bufs make_layout(char* ws, long rows) {
  size_t off = 0;
  auto al = [&](size_t b) -> void* {
    void* p = ws + off;
    off += (b + 255) & ~(size_t)255;
    return p;
  };
  Bufs B;
  B.Wqkv = (bf16*)al((size_t)6 * 1536 * 512 * 2);
  B.Wo = (bf16*)al((size_t)6 * 512 * 512 * 2);
  B.W1 = (bf16*)al((size_t)6 * 2048 * 512 * 2);
  B.W2 = (bf16*)al((size_t)6 * 512 * 2048 * 2);
  B.bqkv = (float*)al((size_t)6 * 1536 * 4);
  B.xsbf = (bf16*)al((size_t)8192 * 128 * 2);
  B.wemb = (bf16*)al((size_t)512 * 128 * 2);
  B.e = (bf16*)al((size_t)8192 * 512 * 2);
  B.x = (bf16*)al((size_t)rows * 512 * 2);
  B.h = (bf16*)al((size_t)rows * 512 * 2);
  B.qkv = (bf16*)al((size_t)rows * 1536 * 2);   // qkv and attn contiguous:
  B.attn = (bf16*)al((size_t)rows * 512 * 2);   // ff[rows][2048] aliases both
  B.need = off;
  return B;
}

extern "C" void kernel_launch(void* const* d_in, const int* in_sizes, int n_in, void* d_out,
                              int out_size, void* d_ws, size_t ws_size, hipStream_t stream) {
  const float* xs = (const float*)d_in[0];
  const int* masks = (const int*)d_in[1];
  const float* emb_w = (const float*)d_in[2];
  const float* emb_b = (const float*)d_in[3];
  const float* emb_g = (const float*)d_in[4];
  const float* emb_beta = (const float*)d_in[5];
  const float* wq = (const float*)d_in[6];
  const float* bq = (const float*)d_in[7];
  const float* wk = (const float*)d_in[8];
  const float* bk = (const float*)d_in[9];
  const float* wv = (const float*)d_in[10];
  const float* bv = (const float*)d_in[11];
  const float* wo = (const float*)d_in[12];
  const float* bo = (const float*)d_in[13];
  const float* ln1g = (const float*)d_in[14];
  const float* ln1b = (const float*)d_in[15];
  const float* ln2g = (const float*)d_in[16];
  const float* ln2b = (const float*)d_in[17];
  const float* f1w = (const float*)d_in[18];
  const float* f1b = (const float*)d_in[19];
  const float* f2w = (const float*)d_in[20];
  const float* f2b = (const float*)d_in[21];
  const float* fing = (const float*)d_in[22];
  const float* finb = (const float*)d_in[23];

  char* ws = (char*)d_ws;
  Bufs bm = make_layout(ws, 16384);
  const bool merged = bm.need <= ws_size;
  Bufs b = merged ? bm : make_layout(ws, 8192);
  const long rows = merged ? 16384 : 8192;
  const int npass = merged ? 1 : 2;
  const int mg = (int)(rows / 128);
  const int zdim = (int)(rows / 8192);
  const float QS = 0.18033688011112042f;  // 0.125 * log2(e)

  // weight prep
  trconv_kernel<<<dim3(16, 16, 6), 256, 0, stream>>>(wq, b.Wqkv, 512, 512, (long)512 * 512,
                                                     (long)1536 * 512);
  trconv_kernel<<<dim3(16, 16, 6), 256, 0, stream>>>(wk, b.Wqkv + 512 * 512, 512, 512,
                                                     (long)512 * 512, (long)1536 * 512);
  trconv_kernel<<<dim3(16, 16, 6), 256, 0, stream>>>(wv, b.Wqkv + 1024 * 512, 512, 512,
                                                     (long)512 * 512, (long)1536 * 512);
  trconv_kernel<<<dim3(16, 16, 6), 256, 0, stream>>>(wo, b.Wo, 512, 512, (long)512 * 512,
                                                     (long)512 * 512);
  trconv_kernel<<<dim3(64, 16, 6), 256, 0, stream>>>(f1w, b.W1, 512, 2048, (long)512 * 2048,
                                                     (long)2048 * 512);
  trconv_kernel<<<dim3(16, 64, 6), 256, 0, stream>>>(f2w, b.W2, 2048, 512, (long)2048 * 512,
                                                     (long)512 * 2048);
  biascat_kernel<<<36, 256, 0, stream>>>(bq, bk, bv, b.bqkv);
  xsconv_kernel<<<(8192 * 128 + 255) / 256, 256, 0, stream>>>(xs, b.xsbf);
  embwconv_kernel<<<(512 * 128 + 255) / 256, 256, 0, stream>>>(emb_w, b.wemb);

  for (int pass = 0; pass < npass; ++pass) {
    // embed GEMM: e[8192,512] = xsbf[8192,128] @ wemb^T + emb_b
    gemm_kernel<false><<<dim3(64, 4), 256, 0, stream>>>(b.xsbf, b.wemb, emb_b, b.e, 8192, 512,
                                                        128, 1.0f, 0);
    posenc_ln_kernel<<<8192, 256, 0, stream>>>(b.e, emb_g, emb_beta, ln1g, ln1b, b.x, b.h, zdim);
    for (int l = 0; l < 6; ++l) {
      gemm_kernel<false><<<dim3(mg, 12), 256, 0, stream>>>(b.h, b.Wqkv + (size_t)l * 1536 * 512,
                                                           b.bqkv + l * 1536, b.qkv, (int)rows,
                                                           1536, 512, QS, 512);
      attn_kernel<<<dim3(8, 64, zdim), 512, 0, stream>>>(b.qkv, b.attn, merged ? 0 : pass);
      gemm_kernel<false><<<dim3(mg, 4), 256, 0, stream>>>(b.attn, b.Wo + (size_t)l * 512 * 512,
                                                          bo + l * 512, b.h, (int)rows, 512, 512,
                                                          1.0f, 0);
      add_ln_kernel<0><<<(int)(rows / 4), 256, 0, stream>>>(b.x, b.h, ln2g + l * 512,
                                                            ln2b + l * 512, b.h);
      gemm_kernel<true><<<dim3(mg, 16), 256, 0, stream>>>(b.h, b.W1 + (size_t)l * 2048 * 512,
                                                          f1b + l * 2048, b.qkv /*ff*/, (int)rows,
                                                          2048, 512, 1.0f, 0);
      gemm_kernel<false><<<dim3(mg, 4), 256, 0, stream>>>(b.qkv /*ff*/,
                                                          b.W2 + (size_t)l * 512 * 2048,
                                                          f2b + l * 512, b.h, (int)rows, 512,
                                                          2048, 1.0f, 0);
      if (l < 5)
        add_ln_kernel<0><<<(int)(rows / 4), 256, 0, stream>>>(b.x, b.h, ln1g + (l + 1) * 512,
                                                              ln1b + (l + 1) * 512, b.h);
      else
        add_ln_kernel<1><<<(int)(rows / 4), 256, 0, stream>>>(
            b.x, b.h, fing, finb, (float*)d_out + (size_t)pass * 8192 * 512);
    }
  }
  maskout_kernel<<<32, 256, 0, stream>>>(masks, (float*)d_out + (size_t)2 * 8192 * 512, 8192);
  (void)in_sizes;
  (void)n_in;
  (void)out_size;
}

// Round 19
// 1294.310 us; speedup vs baseline: 1.2347x; 1.2347x over previous
//
#include <hip/hip_runtime.h>
#include <hip/hip_bf16.h>
#include <cstdint>

typedef __hip_bfloat16 bf16;
typedef __attribute__((ext_vector_type(8))) short v8s;
typedef __attribute__((ext_vector_type(4))) float v4f;

#define SWZ(base, row, bytecol) ((base) + (row) * 128 + ((bytecol) ^ (((row) & 7) << 4)))

__device__ __forceinline__ void gload16(const void* g, void* l) {
  __builtin_amdgcn_global_load_lds((__attribute__((address_space(1))) void*)g,
                                   (__attribute__((address_space(3))) void*)l, 16, 0, 0);
}

__device__ __forceinline__ v4f mfma16(v8s a, v8s b, v4f c) {
  return __builtin_amdgcn_mfma_f32_16x16x32_bf16(a, b, c, 0, 0, 0);
}

// bare v_exp_f32 (2^x) — avoids OCML exp2f fixup path
__device__ __forceinline__ float exp2_raw(float x) {
  float r;
  asm("v_exp_f32 %0, %1" : "=v"(r) : "v"(x));
  return r;
}

// raw barrier: lgkmcnt(0) for own-LDS visibility, NO vmcnt drain (keeps prefetch in flight)
__device__ __forceinline__ void pipe_barrier() {
  asm volatile("s_waitcnt lgkmcnt(0)" ::: "memory");
  __builtin_amdgcn_s_barrier();
  asm volatile("" ::: "memory");
}

__device__ __forceinline__ float bu2f(unsigned short u) {
  return __uint_as_float((unsigned)u << 16);
}
__device__ __forceinline__ unsigned short f2bu(float f) {
  bf16 b = __float2bfloat16(f);
  return *(unsigned short*)&b;
}
__device__ __forceinline__ unsigned packbf(float a, float b) {
  return (unsigned)f2bu(a) | ((unsigned)f2bu(b) << 16);
}

__device__ __forceinline__ float blocksum(float v, float* red, int tid) {
#pragma unroll
  for (int o = 32; o > 0; o >>= 1) v += __shfl_xor(v, o);
  if ((tid & 63) == 0) red[tid >> 6] = v;
  __syncthreads();
  float r = red[0] + red[1] + red[2] + red[3];
  __syncthreads();
  return r;
}

// ---------------- xs f32[8192][80] -> bf16[8192][128] (zero-pad K) ----------------
__global__ __launch_bounds__(256) void xsconv_kernel(const float* __restrict__ xs,
                                                     bf16* __restrict__ dst) {
  const int i = blockIdx.x * 256 + threadIdx.x;
  if (i >= 8192 * 128) return;
  const int row = i >> 7, col = i & 127;
  dst[i] = __float2bfloat16(col < 80 ? xs[row * 80 + col] : 0.0f);
}

// ---------------- emb_w f32[80][512] -> bf16[512][128] transposed+padded ----------------
__global__ __launch_bounds__(256) void embwconv_kernel(const float* __restrict__ w,
                                                       bf16* __restrict__ dst) {
  const int i = blockIdx.x * 256 + threadIdx.x;
  if (i >= 512 * 128) return;
  const int n = i >> 7, k = i & 127;
  dst[i] = __float2bfloat16(k < 80 ? w[k * 512 + n] : 0.0f);
}

// ---------------- fused LN(emb)->relu->posenc->x ; LN1(x)->h ; writes both stacks ----------------
__global__ __launch_bounds__(256) void posenc_ln_kernel(
    const bf16* __restrict__ e, const float* __restrict__ g, const float* __restrict__ beta,
    const float* __restrict__ ln1g, const float* __restrict__ ln1b, bf16* __restrict__ x,
    bf16* __restrict__ h, int zdim) {
  const int tok = blockIdx.x;  // 0..8191
  const int tid = threadIdx.x;
  __shared__ float red[4];
  const int c0 = 2 * tid, c1 = 2 * tid + 1;
  const unsigned ev = *(const unsigned*)(e + (long)tok * 512 + c0);
  float v0 = bu2f((unsigned short)ev);
  float v1 = bu2f((unsigned short)(ev >> 16));
  const float mean = blocksum(v0 + v1, red, tid) * (1.0f / 512.0f);
  const float d0 = v0 - mean, d1 = v1 - mean;
  const float var = blocksum(d0 * d0 + d1 * d1, red, tid) * (1.0f / 512.0f);
  const float inv = rsqrtf(var + 1e-12f);
  const float r0 = fmaxf(d0 * inv * g[c0] + beta[c0], 0.0f);
  const float r1 = fmaxf(d1 * inv * g[c1] + beta[c1], 0.0f);
  const int t = tok & 1023;
  const float a = (float)t * __expf((float)c0 * (-9.210340371976184f / 512.0f));
  float sa, ca;
  __sincosf(a, &sa, &ca);
  const float x0 = r0 * 22.627416997969522f + sa;
  const float x1 = r1 * 22.627416997969522f + ca;
  // LN1
  const float m2 = blocksum(x0 + x1, red, tid) * (1.0f / 512.0f);
  const float e0 = x0 - m2, e1 = x1 - m2;
  const float vv = blocksum(e0 * e0 + e1 * e1, red, tid) * (1.0f / 512.0f);
  const float iv = rsqrtf(vv + 1e-12f);
  const float h0 = e0 * iv * ln1g[c0] + ln1b[c0];
  const float h1 = e1 * iv * ln1g[c1] + ln1b[c1];
  const unsigned xp = packbf(x0, x1);
  const unsigned hp = packbf(h0, h1);
  for (int z = 0; z < zdim; ++z) {
    const long row = tok + (long)z * 8192;
    *(unsigned*)(x + row * 512 + c0) = xp;
    *(unsigned*)(h + row * 512 + c0) = hp;
  }
}

// ---------------- fused residual add + LayerNorm, ONE WAVE PER ROW ----------------
template <int FINAL>
__global__ __launch_bounds__(256) void add_ln_kernel(bf16* __restrict__ x,
                                                     const bf16* __restrict__ y,
                                                     const float* __restrict__ g,
                                                     const float* __restrict__ bta,
                                                     void* __restrict__ outp) {
  const int lane = threadIdx.x & 63;
  const long row = (long)blockIdx.x * 4 + (threadIdx.x >> 6);
  const int c = lane * 8;
  const long i0 = row * 512 + c;
  const uint4 xv = *(const uint4*)(x + i0);
  const uint4 yv = *(const uint4*)(y + i0);
  const unsigned* xp = (const unsigned*)&xv;
  const unsigned* yp = (const unsigned*)&yv;
  float v[8];
#pragma unroll
  for (int j = 0; j < 4; ++j) {
    v[2 * j] = bu2f((unsigned short)xp[j]) + bu2f((unsigned short)yp[j]);
    v[2 * j + 1] = bu2f((unsigned short)(xp[j] >> 16)) + bu2f((unsigned short)(yp[j] >> 16));
  }
  if (!FINAL) {
    uint4 w;
    unsigned* wp = (unsigned*)&w;
#pragma unroll
    for (int j = 0; j < 4; ++j) wp[j] = packbf(v[2 * j], v[2 * j + 1]);
    *(uint4*)(x + i0) = w;
  }
  float s = ((v[0] + v[1]) + (v[2] + v[3])) + ((v[4] + v[5]) + (v[6] + v[7]));
#pragma unroll
  for (int o = 32; o > 0; o >>= 1) s += __shfl_xor(s, o);
  const float mean = s * (1.0f / 512.0f);
  float q = 0.0f;
#pragma unroll
  for (int j = 0; j < 8; ++j) {
    v[j] -= mean;
    q += v[j] * v[j];
  }
#pragma unroll
  for (int o = 32; o > 0; o >>= 1) q += __shfl_xor(q, o);
  const float inv = rsqrtf(q * (1.0f / 512.0f) + 1e-12f);
  const float4 g0 = *(const float4*)(g + c);
  const float4 g1 = *(const float4*)(g + c + 4);
  const float4 b0 = *(const float4*)(bta + c);
  const float4 b1 = *(const float4*)(bta + c + 4);
  float o0 = v[0] * inv * g0.x + b0.x, o1 = v[1] * inv * g0.y + b0.y;
  float o2 = v[2] * inv * g0.z + b0.z, o3 = v[3] * inv * g0.w + b0.w;
  float o4 = v[4] * inv * g1.x + b1.x, o5 = v[5] * inv * g1.y + b1.y;
  float o6 = v[6] * inv * g1.z + b1.z, o7 = v[7] * inv * g1.w + b1.w;
  if (FINAL) {
    float4* o = (float4*)((float*)outp + i0);
    o[0] = make_float4(o0, o1, o2, o3);
    o[1] = make_float4(o4, o5, o6, o7);
  } else {
    uint4 w;
    w.x = packbf(o0, o1);
    w.y = packbf(o2, o3);
    w.z = packbf(o4, o5);
    w.w = packbf(o6, o7);
    *(uint4*)((bf16*)outp + i0) = w;
  }
}

// ---------------- weight convert f32[K][N] -> bf16[N][K] (transposed) ----------------
__global__ __launch_bounds__(256) void trconv_kernel(const float* __restrict__ src,
                                                     bf16* __restrict__ dst, int K, int N,
                                                     long src_lstride, long dst_lstride) {
  __shared__ float tile[32][33];
  src += (long)blockIdx.z * src_lstride;
  dst += (long)blockIdx.z * dst_lstride;
  const int n0 = blockIdx.x * 32, k0 = blockIdx.y * 32;
  const int tx = threadIdx.x & 31, ty = threadIdx.x >> 5;
#pragma unroll
  for (int i = 0; i < 32; i += 8)
    tile[ty + i][tx] = src[(long)(k0 + ty + i) * N + n0 + tx];
  __syncthreads();
#pragma unroll
  for (int i = 0; i < 32; i += 8)
    dst[(long)(n0 + ty + i) * K + k0 + tx] = __float2bfloat16(tile[tx][ty + i]);
}

__global__ void biascat_kernel(const float* bq, const float* bk, const float* bv, float* o) {
  const int i = blockIdx.x * 256 + threadIdx.x;
  if (i >= 6 * 1536) return;
  const int l = i / 1536, n = i % 1536;
  o[i] = (n < 512) ? bq[l * 512 + n] : (n < 1024) ? bk[l * 512 + n - 512] : bv[l * 512 + n - 1024];
}

__global__ void maskout_kernel(const int* m, float* o, int n) {
  const int i = blockIdx.x * 256 + threadIdx.x;
  if (i < n) o[i] = m[i] ? 1.0f : 0.0f;
}

// ---------------- GEMM 128x128: C = (A @ W^T + bias) * sc ----------------
// BK=64, XOR-swizzled LDS, double-buffered, operand-resident XCD partition.
template <bool RELU>
__global__ __launch_bounds__(256) void gemm_kernel(const bf16* __restrict__ A,
                                                   const bf16* __restrict__ W,
                                                   const float* __restrict__ bias,
                                                   bf16* __restrict__ outp, int M, int N, int K,
                                                   float qsc, int qcols) {
  __shared__ __align__(16) bf16 As[2][128 * 64];
  __shared__ __align__(16) bf16 Bs[2][128 * 64];
  const int tid = threadIdx.x, lane = tid & 63, wave = tid >> 6;
  int bx, by;
  {
    const int gx = gridDim.x, gy = gridDim.y;
    const int f = (int)blockIdx.y * gx + (int)blockIdx.x;
    if ((gx & 7) == 0) {
      const int xcd = f & 7;
      const int j = f >> 3;
      const int per = gx >> 3;
      by = j % gy;
      bx = xcd * per + j / gy;
    } else {
      bx = blockIdx.x;
      by = blockIdx.y;
    }
  }
  const int m0 = bx * 128, n0 = by * 128;
  const float sc = (n0 < qcols) ? qsc : 1.0f;
  const int wr = (wave >> 1) * 64, wc = (wave & 1) * 64;
  const int colswz = (((tid & 7) ^ ((tid >> 3) & 7)) * 8);
  const bf16* ag = A + (long)(m0 + (tid >> 3)) * K + colswz;
  const bf16* bg = W + (long)(n0 + (tid >> 3)) * K + colswz;
  char* asb = (char*)As + wave * 1024;
  char* bsb = (char*)Bs + wave * 1024;
  v4f acc[4][4] = {};
  const int frow = lane & 15, fch = lane >> 4;
  const int nk = K >> 6;
#pragma unroll
  for (int i = 0; i < 4; ++i) {
    gload16(ag + (long)i * 32 * K, asb + i * 4096);
    gload16(bg + (long)i * 32 * K, bsb + i * 4096);
  }
  for (int t = 0; t < nk; ++t) {
    const int cur = t & 1;
    asm volatile("s_waitcnt vmcnt(0)" ::: "memory");
    __builtin_amdgcn_s_barrier();
    if (t + 1 < nk) {
      const int k0 = (t + 1) << 6;
      const int nb = (cur ^ 1) * 16384;
#pragma unroll
      for (int i = 0; i < 4; ++i) {
        gload16(ag + k0 + (long)i * 32 * K, asb + nb + i * 4096);
        gload16(bg + k0 + (long)i * 32 * K, bsb + nb + i * 4096);
      }
    }
    const char* Ab = (const char*)As[cur];
    const char* Bb = (const char*)Bs[cur];
#pragma unroll
    for (int kk = 0; kk < 2; ++kk) {
      v8s af[4], bfv[4];
#pragma unroll
      for (int m = 0; m < 4; ++m) {
        const int row = wr + m * 16 + frow;
        af[m] = *(const v8s*)(Ab + row * 128 + (((kk * 4 + fch) * 16) ^ ((row & 7) << 4)));
      }
#pragma unroll
      for (int n = 0; n < 4; ++n) {
        const int row = wc + n * 16 + frow;
        bfv[n] = *(const v8s*)(Bb + row * 128 + (((kk * 4 + fch) * 16) ^ ((row & 7) << 4)));
      }
#pragma unroll
      for (int m = 0; m < 4; ++m)
#pragma unroll
        for (int n = 0; n < 4; ++n)
          acc[m][n] = mfma16(af[m], bfv[n], acc[m][n]);
    }
  }
  float bv[4];
#pragma unroll
  for (int n = 0; n < 4; ++n) bv[n] = bias[n0 + wc + n * 16 + frow];
#pragma unroll
  for (int m = 0; m < 4; ++m) {
#pragma unroll
    for (int n = 0; n < 4; ++n) {
#pragma unroll
      for (int r = 0; r < 4; ++r) {
        const int row = m0 + wr + m * 16 + fch * 4 + r;
        const int col = n0 + wc + n * 16 + frow;
        float v = (acc[m][n][r] + bv[n]) * sc;
        if (RELU) v = fmaxf(v, 0.0f);
        outp[(long)row * N + col] = __float2bfloat16(v);
      }
    }
  }
}

// ---------------- fused flash attention (swapped-QK^T, in-lane softmax) ----------------
// Q pre-scaled by 0.125*log2e (QKV-GEMM epilogue) -> scores in log2 domain:
// softmax = sub + bare v_exp_f32 only. Defer-rescale (THR=3 log2 units, P<=8),
// deferred cross-lane l-reduction (esc row-uniform -> per-lane partials consistent).
__global__ __launch_bounds__(512) void attn_kernel(const bf16* __restrict__ qkv,
                                                   bf16* __restrict__ aout, int chunk0) {
  __shared__ __align__(16) char QPs[128 * 128];   // Q tile, then per-wave P strips
  __shared__ __align__(16) char Ks[2][64 * 128];
  __shared__ __align__(16) char Vs[2][64 * 128];  // V^T: [d][key*2 ^ (((d>>3)^(d&7))<<4)]
  const int tid = threadIdx.x, lane = tid & 63, wave = tid >> 6;
  int qb, bh, zz;
  {
    const int zdim = (int)gridDim.z;            // 1 or 2
    const int nwg = 512 * zdim;
    const int flat = (int)blockIdx.x + 8 * (int)blockIdx.y + 512 * (int)blockIdx.z;
    const int s = (flat & 7) * (nwg >> 3) + (flat >> 3);
    qb = s & 7;
    const int rest = s >> 3;                    // = bh*zdim + zz  (zz fastest)
    zz = rest & (zdim - 1);
    bh = rest >> (zdim >> 1);
  }
  const int chunked = chunk0 + zz;
  const long tb = (long)zz * 8192 + (long)(bh >> 3) * 1024;
  const int hh = bh & 7;
  const int q0 = qb * 128;
  const int sr = tid >> 3, ss = tid & 7;
  int kt0 = 0, kt1 = 16;
  if (chunked) {
    kt0 = qb * 2 - 1;
    if (kt0 < 0) kt0 = 0;
    kt1 = qb * 2 + 2;
  }
  uint4 kreg, vreg;
  {
    const long ro = (tb + kt0 * 64 + sr) * 1536 + hh * 64 + ss * 8;
    kreg = *(const uint4*)(qkv + ro + 512);
    vreg = *(const uint4*)(qkv + ro + 1024);
  }
#pragma unroll
  for (int p = 0; p < 2; ++p) {
    const int rr = sr + p * 64;
    const uint4 d = *(const uint4*)(qkv + (tb + q0 + rr) * 1536 + hh * 64 + ss * 8);
    *(uint4*)(QPs + rr * 128 + ((ss * 16) ^ ((rr & 7) << 4))) = d;
  }
  pipe_barrier();  // [A] Q visible
  const int frow = lane & 15, fch = lane >> 4;
  const v8s qa0 = *(const v8s*)SWZ(QPs, wave * 16 + frow, fch * 16);
  const v8s qa1 = *(const v8s*)SWZ(QPs, wave * 16 + frow, 64 + fch * 16);
  // stage buf0, issue tile kt0+1
  *(uint4*)(Ks[0] + sr * 128 + ((ss * 16) ^ ((sr & 7) << 4))) = kreg;
  {
    const bf16* ve = (const bf16*)&vreg;
#pragma unroll
    for (int e = 0; e < 8; ++e) {
      *(bf16*)(Vs[0] + (ss * 8 + e) * 128 + ((sr * 2) ^ (ss << 4) ^ (e << 4))) = ve[e];
    }
  }
  if (kt0 + 1 < kt1) {
    const long ro = (tb + (kt0 + 1) * 64 + sr) * 1536 + hh * 64 + ss * 8;
    kreg = *(const uint4*)(qkv + ro + 512);
    vreg = *(const uint4*)(qkv + ro + 1024);
  }
  pipe_barrier();  // [B] buf0 visible
  v4f accv[4] = {};
  float m_run = -1e30f, l_run = 0.0f;
  const int qswz = (frow & 7) << 4;
  char* Pw = QPs + wave * 2048;  // own wave's (dead) Q strip: P[q=frow][key]
  const int qb_ = (q0 + wave * 16 + frow) >> 4;  // chunk row (chunked mask), per-lane const
  int cur = 0;
  for (int kt = kt0; kt < kt1; ++kt) {
    if (kt + 1 < kt1) {
      *(uint4*)(Ks[cur ^ 1] + sr * 128 + ((ss * 16) ^ ((sr & 7) << 4))) = kreg;
      const bf16* ve = (const bf16*)&vreg;
#pragma unroll
      for (int e = 0; e < 8; ++e) {
        *(bf16*)(Vs[cur ^ 1] + (ss * 8 + e) * 128 + ((sr * 2) ^ (ss << 4) ^ (e << 4))) = ve[e];
      }
      if (kt + 2 < kt1) {
        const long ro = (tb + (kt + 2) * 64 + sr) * 1536 + hh * 64 + ss * 8;
        kreg = *(const uint4*)(qkv + ro + 512);
        vreg = *(const uint4*)(qkv + ro + 1024);
      }
    }
    const char* Kc = Ks[cur];
    const char* Vc = Vs[cur];
    v4f s4[4];
    __builtin_amdgcn_s_setprio(1);
#pragma unroll
    for (int n = 0; n < 4; ++n) {
      const v8s kb0 = *(const v8s*)SWZ(Kc, n * 16 + frow, fch * 16);
      const v8s kb1 = *(const v8s*)SWZ(Kc, n * 16 + frow, 64 + fch * 16);
      v4f z = {0.f, 0.f, 0.f, 0.f};
      z = mfma16(kb0, qa0, z);  // swapped: S^T tile (log2-domain), lane col = q(frow)
      z = mfma16(kb1, qa1, z);
      s4[n] = z;
    }
    __builtin_amdgcn_s_setprio(0);
    if (chunked) {
#pragma unroll
      for (int n = 0; n < 4; ++n)
#pragma unroll
        for (int r = 0; r < 4; ++r) {
          const int kb_ = (kt * 64 + n * 16 + fch * 4 + r) >> 4;
          if (!(kb_ <= qb_ && qb_ - kb_ <= 4)) s4[n][r] = -1e30f;
        }
    }
    // in-lane row max (16 values for q=frow) + 2 cross-group shuffles
    float u0 = fmaxf(fmaxf(s4[0][0], s4[1][0]), fmaxf(s4[2][0], s4[3][0]));
    float u1 = fmaxf(fmaxf(s4[0][1], s4[1][1]), fmaxf(s4[2][1], s4[3][1]));
    float u2 = fmaxf(fmaxf(s4[0][2], s4[1][2]), fmaxf(s4[2][2], s4[3][2]));
    float u3 = fmaxf(fmaxf(s4[0][3], s4[1][3]), fmaxf(s4[2][3], s4[3][3]));
    float mt = fmaxf(fmaxf(u0, u1), fmaxf(u2, u3));
    mt = fmaxf(mt, __shfl_xor(mt, 16));
    mt = fmaxf(mt, __shfl_xor(mt, 32));
    // defer-rescale: only when row max grew past 3.0 log2 units (P <= 8)
    if (!__all(mt <= m_run + 3.0f)) {
      const float mnew = fmaxf(m_run, mt);
      const float esc = exp2_raw(m_run - mnew);
      l_run *= esc;
#pragma unroll
      for (int f = 0; f < 4; ++f)
#pragma unroll
        for (int r = 0; r < 4; ++r) accv[f][r] *= esc;
      m_run = mnew;
    }
#pragma unroll
    for (int n = 0; n < 4; ++n)
#pragma unroll
      for (int r = 0; r < 4; ++r) s4[n][r] = exp2_raw(s4[n][r] - m_run);
    l_run += ((s4[0][0] + s4[1][0]) + (s4[2][0] + s4[3][0])) +
             ((s4[0][1] + s4[1][1]) + (s4[2][1] + s4[3][1])) +
             ((s4[0][2] + s4[1][2]) + (s4[2][2] + s4[3][2])) +
             ((s4[0][3] + s4[1][3]) + (s4[2][3] + s4[3][3]));
    // P[q=frow][key = fch*4 + r + 16n] -> 4x 8B swizzled writes
#pragma unroll
    for (int n = 0; n < 4; ++n) {
      uint2 w;
      w.x = packbf(s4[n][0], s4[n][1]);
      w.y = packbf(s4[n][2], s4[n][3]);
      *(uint2*)(Pw + frow * 128 + ((fch * 8 + 32 * n) ^ qswz)) = w;
    }
    const v8s pa0 = *(const v8s*)(Pw + frow * 128 + ((fch * 16) ^ qswz));
    const v8s pa1 = *(const v8s*)(Pw + frow * 128 + ((64 + fch * 16) ^ qswz));
    __builtin_amdgcn_s_setprio(1);
#pragma unroll
    for (int f = 0; f < 4; ++f) {
      const int vh = (((f * 2 + (frow >> 3)) ^ (frow & 7)) & 7) << 4;
      const int drow = (f * 16 + frow) * 128;
      const v8s vb0 = *(const v8s*)(Vc + drow + ((fch * 16) ^ vh));
      const v8s vb1 = *(const v8s*)(Vc + drow + ((64 + fch * 16) ^ vh));
      accv[f] = mfma16(vb0, pa0, accv[f]);  // O^T: lane col = q(frow), row = d
      accv[f] = mfma16(vb1, pa1, accv[f]);
    }
    __builtin_amdgcn_s_setprio(0);
    pipe_barrier();
    cur ^= 1;
  }
  // deferred cross-lane l reduction (esc was row-uniform each tile)
  l_run += __shfl_xor(l_run, 16);
  l_run += __shfl_xor(l_run, 32);
  const float rl = 1.0f / l_run;
  const long orow = (tb + q0 + wave * 16 + frow) * 512 + hh * 64;
#pragma unroll
  for (int f = 0; f < 4; ++f) {
    uint2 u;
    u.x = packbf(accv[f][0] * rl, accv[f][1] * rl);
    u.y = packbf(accv[f][2] * rl, accv[f][3] * rl);
    *(uint2*)(aout + orow + f * 16 + fch * 4) = u;
  }
}

struct Bufs {
  bf16 *Wqkv, *Wo, *W1, *W2;
  float* bqkv;
  bf16 *xsbf, *wemb, *e;
  bf16* x;
  bf16 *h, *qkv, *attn;
  size_t need;
};

static Bufs make_layout(char* ws, long rows) {
  size_t off = 0;
  auto al = [&](size_t b) -> void* {
    void* p = ws + off;
    off += (b + 255) & ~(size_t)255;
    return p;
  };
  Bufs B;
  B.Wqkv = (bf16*)al((size_t)6 * 1536 * 512 * 2);
  B.Wo = (bf16*)al((size_t)6 * 512 * 512 * 2);
  B.W1 = (bf16*)al((size_t)6 * 2048 * 512 * 2);
  B.W2 = (bf16*)al((size_t)6 * 512 * 2048 * 2);
  B.bqkv = (float*)al((size_t)6 * 1536 * 4);
  B.xsbf = (bf16*)al((size_t)8192 * 128 * 2);
  B.wemb = (bf16*)al((size_t)512 * 128 * 2);
  B.e = (bf16*)al((size_t)8192 * 512 * 2);
  B.x = (bf16*)al((size_t)rows * 512 * 2);
  B.h = (bf16*)al((size_t)rows * 512 * 2);
  B.qkv = (bf16*)al((size_t)rows * 1536 * 2);   // qkv and attn contiguous:
  B.attn = (bf16*)al((size_t)rows * 512 * 2);   // ff[rows][2048] aliases both
  B.need = off;
  return B;
}

extern "C" void kernel_launch(void* const* d_in, const int* in_sizes, int n_in, void* d_out,
                              int out_size, void* d_ws, size_t ws_size, hipStream_t stream) {
  const float* xs = (const float*)d_in[0];
  const int* masks = (const int*)d_in[1];
  const float* emb_w = (const float*)d_in[2];
  const float* emb_b = (const float*)d_in[3];
  const float* emb_g = (const float*)d_in[4];
  const float* emb_beta = (const float*)d_in[5];
  const float* wq = (const float*)d_in[6];
  const float* bq = (const float*)d_in[7];
  const float* wk = (const float*)d_in[8];
  const float* bk = (const float*)d_in[9];
  const float* wv = (const float*)d_in[10];
  const float* bv = (const float*)d_in[11];
  const float* wo = (const float*)d_in[12];
  const float* bo = (const float*)d_in[13];
  const float* ln1g = (const float*)d_in[14];
  const float* ln1b = (const float*)d_in[15];
  const float* ln2g = (const float*)d_in[16];
  const float* ln2b = (const float*)d_in[17];
  const float* f1w = (const float*)d_in[18];
  const float* f1b = (const float*)d_in[19];
  const float* f2w = (const float*)d_in[20];
  const float* f2b = (const float*)d_in[21];
  const float* fing = (const float*)d_in[22];
  const float* finb = (const float*)d_in[23];

  char* ws = (char*)d_ws;
  Bufs bm = make_layout(ws, 16384);
  const bool merged = bm.need <= ws_size;
  Bufs b = merged ? bm : make_layout(ws, 8192);
  const long rows = merged ? 16384 : 8192;
  const int npass = merged ? 1 : 2;
  const int mg = (int)(rows / 128);
  const int zdim = (int)(rows / 8192);
  const float QS = 0.18033688011112042f;  // 0.125 * log2(e)

  // weight prep
  trconv_kernel<<<dim3(16, 16, 6), 256, 0, stream>>>(wq, b.Wqkv, 512, 512, (long)512 * 512,
                                                     (long)1536 * 512);
  trconv_kernel<<<dim3(16, 16, 6), 256, 0, stream>>>(wk, b.Wqkv + 512 * 512, 512, 512,
                                                     (long)512 * 512, (long)1536 * 512);
  trconv_kernel<<<dim3(16, 16, 6), 256, 0, stream>>>(wv, b.Wqkv + 1024 * 512, 512, 512,
                                                     (long)512 * 512, (long)1536 * 512);
  trconv_kernel<<<dim3(16, 16, 6), 256, 0, stream>>>(wo, b.Wo, 512, 512, (long)512 * 512,
                                                     (long)512 * 512);
  trconv_kernel<<<dim3(64, 16, 6), 256, 0, stream>>>(f1w, b.W1, 512, 2048, (long)512 * 2048,
                                                     (long)2048 * 512);
  trconv_kernel<<<dim3(16, 64, 6), 256, 0, stream>>>(f2w, b.W2, 2048, 512, (long)2048 * 512,
                                                     (long)512 * 2048);
  biascat_kernel<<<36, 256, 0, stream>>>(bq, bk, bv, b.bqkv);
  xsconv_kernel<<<(8192 * 128 + 255) / 256, 256, 0, stream>>>(xs, b.xsbf);
  embwconv_kernel<<<(512 * 128 + 255) / 256, 256, 0, stream>>>(emb_w, b.wemb);

  for (int pass = 0; pass < npass; ++pass) {
    // embed GEMM: e[8192,512] = xsbf[8192,128] @ wemb^T + emb_b
    gemm_kernel<false><<<dim3(64, 4), 256, 0, stream>>>(b.xsbf, b.wemb, emb_b, b.e, 8192, 512,
                                                        128, 1.0f, 0);
    posenc_ln_kernel<<<8192, 256, 0, stream>>>(b.e, emb_g, emb_beta, ln1g, ln1b, b.x, b.h, zdim);
    for (int l = 0; l < 6; ++l) {
      gemm_kernel<false><<<dim3(mg, 12), 256, 0, stream>>>(b.h, b.Wqkv + (size_t)l * 1536 * 512,
                                                           b.bqkv + l * 1536, b.qkv, (int)rows,
                                                           1536, 512, QS, 512);
      attn_kernel<<<dim3(8, 64, zdim), 512, 0, stream>>>(b.qkv, b.attn, merged ? 0 : pass);
      gemm_kernel<false><<<dim3(mg, 4), 256, 0, stream>>>(b.attn, b.Wo + (size_t)l * 512 * 512,
                                                          bo + l * 512, b.h, (int)rows, 512, 512,
                                                          1.0f, 0);
      add_ln_kernel<0><<<(int)(rows / 4), 256, 0, stream>>>(b.x, b.h, ln2g + l * 512,
                                                            ln2b + l * 512, b.h);
      gemm_kernel<true><<<dim3(mg, 16), 256, 0, stream>>>(b.h, b.W1 + (size_t)l * 2048 * 512,
                                                          f1b + l * 2048, b.qkv /*ff*/, (int)rows,
                                                          2048, 512, 1.0f, 0);
      gemm_kernel<false><<<dim3(mg, 4), 256, 0, stream>>>(b.qkv /*ff*/,
                                                          b.W2 + (size_t)l * 512 * 2048,
                                                          f2b + l * 512, b.h, (int)rows, 512,
                                                          2048, 1.0f, 0);
      if (l < 5)
        add_ln_kernel<0><<<(int)(rows / 4), 256, 0, stream>>>(b.x, b.h, ln1g + (l + 1) * 512,
                                                              ln1b + (l + 1) * 512, b.h);
      else
        add_ln_kernel<1><<<(int)(rows / 4), 256, 0, stream>>>(
            b.x, b.h, fing, finb, (float*)d_out + (size_t)pass * 8192 * 512);
    }
  }
  maskout_kernel<<<32, 256, 0, stream>>>(masks, (float*)d_out + (size_t)2 * 8192 * 512, 8192);
  (void)in_sizes;
  (void)n_in;
  (void)out_size;
}